// Round 5
// baseline (789.874 us; speedup 1.0000x reference)
//
#include <hip/hip_runtime.h>
#include <hip/hip_bf16.h>

#define NNODES 50000
#define NEDGES 400000
#define NGRAPH 16

typedef __attribute__((ext_vector_type(4))) float floatx4;
typedef __attribute__((ext_vector_type(8))) short short8;

typedef __attribute__((address_space(3))) unsigned int lds_uint;
typedef __attribute__((address_space(1))) const unsigned int gbl_uint;

__device__ __forceinline__ void load16_to_lds(const void* g, void* l) {
    __builtin_amdgcn_global_load_lds((gbl_uint*)g, (lds_uint*)l, 16, 0, 0);
}

// ---------------------------------------------------------------------------
__global__ __launch_bounds__(64) void zero_out_k(float* out, int n) {
    int i = blockIdx.x * 64 + threadIdx.x;
    if (i < n) out[i] = 0.0f;
}

// init: zero counters/accumulators + pack x rows into float4
__global__ __launch_bounds__(256) void init_k(int* deg_cnt, int* cursor,
                                              float* gsum, int* gcnt,
                                              const float* __restrict__ x,
                                              float4* __restrict__ xp, int n) {
    int i = blockIdx.x * 256 + threadIdx.x;
    if (i < n) {
        deg_cnt[i] = 0; cursor[i] = 0;
        xp[i] = make_float4(x[i * 3 + 0], x[i * 3 + 1], x[i * 3 + 2], 0.0f);
    }
    if (i < NGRAPH * 512) gsum[i] = 0.0f;
    if (i < NGRAPH) gcnt[i] = 0;
}

__global__ __launch_bounds__(256) void deg_k(const int* __restrict__ col,
                                             int* __restrict__ deg_cnt, int e) {
    int i = blockIdx.x * 256 + threadIdx.x;
    if (i < e) atomicAdd(&deg_cnt[col[i]], 1);
}

// ---- parallel 3-phase scan ----
__global__ __launch_bounds__(256) void segsum_k(const int* __restrict__ cnt,
                                                int* __restrict__ segsum, int n) {
    __shared__ int sb[256];
    int seg = blockIdx.x;
    int base = seg * 1024;
    int t = threadIdx.x;
    int s = 0;
#pragma unroll
    for (int j = 0; j < 4; ++j) {
        int idx = base + t + j * 256;
        if (idx < n) s += cnt[idx];
    }
    sb[t] = s;
    __syncthreads();
    for (int off = 128; off > 0; off >>= 1) {
        if (t < off) sb[t] += sb[t + off];
        __syncthreads();
    }
    if (t == 0) segsum[seg] = sb[0];
}

__global__ __launch_bounds__(64) void segscan_k(const int* __restrict__ segsum,
                                                int* __restrict__ segbase,
                                                int* __restrict__ offs,
                                                int nseg, int n) {
    if (threadIdx.x == 0) {
        int run = 0;
        for (int s = 0; s < nseg; ++s) { segbase[s] = run; run += segsum[s]; }
        offs[n] = run;
    }
}

__global__ __launch_bounds__(1024) void offs_k(const int* __restrict__ cnt,
                                               const int* __restrict__ segbase,
                                               int* __restrict__ offs,
                                               float* __restrict__ dis, int n) {
    __shared__ int sb[1024];
    int seg = blockIdx.x;
    int t = threadIdx.x;
    int i = seg * 1024 + t;
    int c = (i < n) ? cnt[i] : 0;
    sb[t] = c;
    __syncthreads();
    for (int off = 1; off < 1024; off <<= 1) {
        int v = (t >= off) ? sb[t - off] : 0;
        __syncthreads();
        sb[t] += v;
        __syncthreads();
    }
    if (i < n) {
        offs[i] = segbase[seg] + sb[t] - c;   // exclusive prefix
        dis[i]  = rsqrtf((float)(c + 1));
    }
}

__global__ __launch_bounds__(256) void scatter_k(const int* __restrict__ row,
                                                 const int* __restrict__ col,
                                                 const int* __restrict__ offs,
                                                 int* __restrict__ cursor,
                                                 int* __restrict__ ssrc,
                                                 float* __restrict__ sw,
                                                 const float* __restrict__ dis, int e) {
    int i = blockIdx.x * 256 + threadIdx.x;
    if (i >= e) return;
    int d = col[i];
    int p = offs[d] + atomicAdd(&cursor[d], 1);
    int s = row[i];
    ssrc[p] = s;
    sw[p]   = dis[s];
}

// aggregate x (F=3)
__global__ __launch_bounds__(256) void agg3_k(const float4* __restrict__ xp,
                                              float* __restrict__ out,
                                              const int* __restrict__ offs,
                                              const int* __restrict__ ssrc,
                                              const float* __restrict__ sw,
                                              const float* __restrict__ dis, int n) {
    int d = blockIdx.x * 256 + threadIdx.x;
    if (d >= n) return;
    float dd = dis[d];
    float4 xd = xp[d];
    float a0 = dd * xd.x, a1 = dd * xd.y, a2 = dd * xd.z;
    int beg = offs[d], end = offs[d + 1];
    for (int e = beg; e < end; ++e) {
        int s = ssrc[e];
        float w = sw[e];
        float4 q = xp[s];
        a0 += w * q.x; a1 += w * q.y; a2 += w * q.z;
    }
    out[d * 3 + 0] = dd * a0;
    out[d * 3 + 1] = dd * a1;
    out[d * 3 + 2] = dd * a2;
}

// h1 = relu(aggx[N,3] @ W1[3,512] + b1) -> bf16; one WAVE per node
__global__ __launch_bounds__(256) void gemm1_k(const float* __restrict__ aggx,
                                               const float* __restrict__ W1,
                                               const float* __restrict__ b1,
                                               __hip_bfloat16* __restrict__ h1, int n) {
    int wave = threadIdx.x >> 6;
    int lane = threadIdx.x & 63;
    int d = blockIdx.x * 4 + wave;
    if (d >= n) return;
    float a0 = aggx[d * 3 + 0], a1 = aggx[d * 3 + 1], a2 = aggx[d * 3 + 2];
    int f0 = lane * 8;
    short8 ov;
#pragma unroll
    for (int j = 0; j < 8; ++j) {
        int f = f0 + j;
        float v = b1[f] + a0 * W1[f] + a1 * W1[512 + f] + a2 * W1[1024 + f];
        __hip_bfloat16 h = __float2bfloat16(fmaxf(v, 0.0f));
        ov[j] = *(short*)&h;
    }
    *(short8*)&h1[(size_t)d * 512 + f0] = ov;
}

__device__ inline float bs2f(short v) {
    return __uint_as_float(((unsigned int)(unsigned short)v) << 16);
}

// aggregation F=512 (R8 config): one WAVE per node
__global__ __launch_bounds__(256) void agg512w_k(const __hip_bfloat16* __restrict__ in,
                                                 __hip_bfloat16* __restrict__ out,
                                                 const int* __restrict__ offs,
                                                 const int* __restrict__ ssrc,
                                                 const float* __restrict__ sw,
                                                 const float* __restrict__ dis,
                                                 const float* __restrict__ bias,
                                                 int relu, int n) {
    int wave = threadIdx.x >> 6;
    int lane = threadIdx.x & 63;
    int d = blockIdx.x * 4 + wave;
    if (d >= n) return;
    float dd = dis[d];
    short8 p = *(const short8*)&in[(size_t)d * 512 + lane * 8];
    float acc[8];
#pragma unroll
    for (int j = 0; j < 8; ++j) acc[j] = dd * bs2f(p[j]);

    int beg = offs[d], end = offs[d + 1];
    int e = beg;
    for (; e + 3 < end; e += 4) {
        int s0 = ssrc[e],     s1 = ssrc[e + 1];
        int s2 = ssrc[e + 2], s3 = ssrc[e + 3];
        float w0 = sw[e],     w1 = sw[e + 1];
        float w2 = sw[e + 2], w3 = sw[e + 3];
        short8 q0 = *(const short8*)&in[(size_t)s0 * 512 + lane * 8];
        short8 q1 = *(const short8*)&in[(size_t)s1 * 512 + lane * 8];
        short8 q2 = *(const short8*)&in[(size_t)s2 * 512 + lane * 8];
        short8 q3 = *(const short8*)&in[(size_t)s3 * 512 + lane * 8];
#pragma unroll
        for (int j = 0; j < 8; ++j) acc[j] += w0 * bs2f(q0[j]);
#pragma unroll
        for (int j = 0; j < 8; ++j) acc[j] += w1 * bs2f(q1[j]);
#pragma unroll
        for (int j = 0; j < 8; ++j) acc[j] += w2 * bs2f(q2[j]);
#pragma unroll
        for (int j = 0; j < 8; ++j) acc[j] += w3 * bs2f(q3[j]);
    }
    for (; e < end; ++e) {
        int s0 = ssrc[e];
        float w0 = sw[e];
        short8 q0 = *(const short8*)&in[(size_t)s0 * 512 + lane * 8];
#pragma unroll
        for (int j = 0; j < 8; ++j) acc[j] += w0 * bs2f(q0[j]);
    }

    short8 ov;
#pragma unroll
    for (int j = 0; j < 8; ++j) {
        float v = acc[j] * dd;
        if (bias) v += bias[lane * 8 + j];
        if (relu) v = fmaxf(v, 0.0f);
        __hip_bfloat16 h = __float2bfloat16(v);
        ov[j] = *(short*)&h;
    }
    *(short8*)&out[(size_t)d * 512 + lane * 8] = ov;
}

// merged transpose+convert for BOTH weight matrices
__global__ __launch_bounds__(256) void tcvt_k(const float* __restrict__ W2,
                                              __hip_bfloat16* __restrict__ w2t,
                                              const float* __restrict__ W3,
                                              __hip_bfloat16* __restrict__ w3t) {
    __shared__ float tile[32][33];
    int t = threadIdx.x;
    const float* W; __hip_bfloat16* Wt;
    int K, N, idx;
    if (blockIdx.x < 512) { W = W2; Wt = w2t; K = 512;  N = 1024; idx = blockIdx.x; }
    else                  { W = W3; Wt = w3t; K = 1024; N = 512;  idx = blockIdx.x - 512; }
    int nbn = N / 32;
    int bn = (idx % nbn) * 32;
    int bk = (idx / nbn) * 32;
    int c = t & 31, r0 = t >> 5;
#pragma unroll
    for (int j = 0; j < 4; ++j) {
        int r = r0 + j * 8;
        tile[r][c] = W[(size_t)(bk + r) * N + bn + c];
    }
    __syncthreads();
#pragma unroll
    for (int j = 0; j < 4; ++j) {
        int r = r0 + j * 8;
        Wt[(size_t)(bn + r) * K + bk + c] = __float2bfloat16(tile[c][r]);
    }
}

// ---------------------------------------------------------------------------
// bf16 MFMA GEMM, 128x256 tile, BK=32, 8 waves of 64x64 (2 row-halves x 4
// col-quarters).  KEY CHANGE (R5): only A goes through global_load_lds/LDS;
// B fragments are loaded DIRECTLY global->VGPR (W2/W3 are 1MB each -> fully
// L2-resident; the congested gload_lds path carries 205MB instead of 616MB).
//   Per K-step/wave: 1 gload_lds (A subtile) + 4 B short8 loads (reg dbuf)
//                    + 4 ds_read_b128 + 16 MFMA.
//   vmcnt(5) before barrier: own outstanding = [A(t),B(t)x4 | A(t+1),B(t+1)x4];
//   retiring to 5 proves A(t)+B(t) landed.  Never 0 until last step.
//   B-frag address: lane reads Bt[(col0+ni*16+(lane&15))*K + k0 + (lane>>4)*8]
//   -- identical permutation to the verified LDS subtile layout.
// LDS: A dbuf 2x4096 shorts (16KB); epilogue reuses smem as [64][264] (33.8KB).
__global__ __launch_bounds__(512, 3) void mfma_gemm256_k(
        const __hip_bfloat16* __restrict__ A,
        const __hip_bfloat16* __restrict__ Bt,
        const float* __restrict__ bias,
        __hip_bfloat16* __restrict__ C,
        int M, int N, int K, int relu, int lnt) {
    __shared__ short smem[17408];   // 34.8 KiB

    int tid  = threadIdx.x;
    int lane = tid & 63;
    int wave = tid >> 6;
    int wm = wave >> 2;            // 0..1 : 64-row half
    int wn = wave & 3;             // 0..3 : 64-col quarter
    int fr = lane & 15;
    int kg = lane >> 4;
    int l4 = lane >> 4;

    // bijective XCD swizzle (grid % 8 == 0 by construction)
    int nwg = gridDim.x;
    int wg  = (blockIdx.x & 7) * (nwg >> 3) + (blockIdx.x >> 3);
    int mt  = wg >> lnt;
    int nt  = wg & ((1 << lnt) - 1);
    int bm  = mt << 7;             // 128-row tiles
    int bn  = nt << 8;             // 256-col tiles

    // A staging: lane l = s*16 + r stages chunk (kchunk s, row r); wave w owns
    // subtile w (16 rows).
    const __hip_bfloat16* pa = A + (size_t)(bm + wave * 16 + fr) * K + kg * 8;
    // B fragment base: lane reads col fr of its quarter, k-span kg*8.
    const __hip_bfloat16* pb = Bt + (size_t)(bn + wn * 64 + fr) * K + kg * 8;
    size_t bstr = (size_t)16 * K;  // 16-col fragment stride in Bt

    floatx4 acc[4][4] = {};
    short8 bfr[2][4];
    short8 af[4];

    int KT = K >> 5;               // 16 (K=512) or 32 (K=1024)

    // prologue: stage A(0), load B(0)
    load16_to_lds(pa, &smem[wave * 512]);
#pragma unroll
    for (int ni = 0; ni < 4; ++ni)
        bfr[0][ni] = *(const short8*)(pb + (size_t)ni * bstr);

    auto step = [&](int p, int t) __attribute__((always_inline)) {
        int more = (t + 1 < KT);
        if (more) {
            int k1 = (t + 1) << 5;
            load16_to_lds(pa + k1, &smem[(p ^ 1) * 4096 + wave * 512]);
#pragma unroll
            for (int ni = 0; ni < 4; ++ni)
                bfr[p ^ 1][ni] = *(const short8*)(pb + (size_t)ni * bstr + k1);
            asm volatile("s_waitcnt vmcnt(5)" ::: "memory");  // A(t),B(t) landed
        } else {
            asm volatile("s_waitcnt vmcnt(0)" ::: "memory");
        }
        __builtin_amdgcn_s_barrier();          // slab t visible to all waves
        const short* sm = &smem[p * 4096];
#pragma unroll
        for (int mi = 0; mi < 4; ++mi)
            af[mi] = *(const short8*)&sm[(wm * 4 + mi) * 512 + lane * 8];
        __builtin_amdgcn_s_setprio(1);
#pragma unroll
        for (int mi = 0; mi < 4; ++mi)
#pragma unroll
            for (int ni = 0; ni < 4; ++ni)
                acc[mi][ni] = __builtin_amdgcn_mfma_f32_16x16x32_bf16(
                    af[mi], bfr[p][ni], acc[mi][ni], 0, 0, 0);
        __builtin_amdgcn_s_setprio(0);
        __builtin_amdgcn_s_barrier();          // reads of slab t done
    };

    for (int t = 0; t < KT; t += 2) {          // KT is even (16 or 32)
        step(0, t);
        step(1, t + 1);
    }

    // ---- epilogue: 2 half-passes (64 rows) through LDS, vector stores ----
    short* Cs = smem;
#pragma unroll
    for (int h = 0; h < 2; ++h) {
        __builtin_amdgcn_s_barrier();
        if (wm == h) {
#pragma unroll
            for (int mi = 0; mi < 4; ++mi) {
#pragma unroll
                for (int ni = 0; ni < 4; ++ni) {
                    int lr = mi * 16 + l4 * 4;
                    int cc = wn * 64 + ni * 16 + fr;
                    float bv = bias ? bias[bn + cc] : 0.0f;
#pragma unroll
                    for (int q = 0; q < 4; ++q) {
                        float v = acc[mi][ni][q] + bv;
                        if (relu) v = fmaxf(v, 0.0f);
                        __hip_bfloat16 hh = __float2bfloat16(v);
                        Cs[(lr + q) * 264 + cc] = *(short*)&hh;
                    }
                }
            }
        }
        __builtin_amdgcn_s_barrier();
#pragma unroll
        for (int i = 0; i < 4; ++i) {
            int idx = tid + 512 * i;           // 2048 = 64 rows x 32 chunks
            int rr = idx >> 5, c8 = idx & 31;
            int grow = bm + h * 64 + rr;
            if (grow < M)
                *(short8*)&C[(size_t)grow * N + bn + c8 * 8] =
                    *(const short8*)&Cs[rr * 264 + c8 * 8];
        }
    }
}

// pooled sums (bf16 input, LDS fp32 accumulators) + fused per-graph counts
__global__ __launch_bounds__(256) void pool_k(const __hip_bfloat16* __restrict__ h,
                                              const int* __restrict__ batch,
                                              float* __restrict__ gsum,
                                              int* __restrict__ gcnt, int n) {
    __shared__ float ls[NGRAPH * 512];
    __shared__ int lcnt[NGRAPH];
    int t = threadIdx.x;
    for (int i = t; i < NGRAPH * 512; i += 256) ls[i] = 0.0f;
    if (t < NGRAPH) lcnt[t] = 0;
    __syncthreads();
    for (int d = blockIdx.x; d < n; d += gridDim.x) {
        int g = batch[d];
        if (t == 0) atomicAdd(&lcnt[g], 1);
        unsigned int q = *(const unsigned int*)&h[(size_t)d * 512 + 2 * t];
        ls[g * 512 + 2 * t]     += __uint_as_float((q & 0xffffu) << 16);
        ls[g * 512 + 2 * t + 1] += __uint_as_float((q >> 16) << 16);
    }
    __syncthreads();
    for (int i = t; i < NGRAPH * 512; i += 256) atomicAdd(&gsum[i], ls[i]);
    if (t < NGRAPH) atomicAdd(&gcnt[t], lcnt[t]);
}

// head MLP (fp32)
__global__ __launch_bounds__(128) void fc_k(const float* __restrict__ gsum,
                                            const int* __restrict__ gcnt,
                                            const float* __restrict__ fcw1,
                                            const float* __restrict__ fcb1,
                                            const float* __restrict__ fcw2,
                                            const float* __restrict__ fcb2,
                                            float* __restrict__ out) {
    int g = blockIdx.x;
    int t = threadIdx.x;  // 128
    __shared__ float pooled[512];
    __shared__ float red[128];
    float inv = 1.0f / fmaxf((float)gcnt[g], 1.0f);
    for (int i = t; i < 512; i += 128) pooled[i] = gsum[g * 512 + i] * inv;
    __syncthreads();
    float sacc = fcb1[t];
    for (int k = 0; k < 512; ++k) sacc += pooled[k] * fcw1[k * 128 + t];
    sacc = fmaxf(sacc, 0.0f);
    red[t] = sacc * fcw2[t];
    __syncthreads();
    for (int off = 64; off > 0; off >>= 1) {
        if (t < off) red[t] += red[t + off];
        __syncthreads();
    }
    if (t == 0) out[g] = red[0] + fcb2[0];
}

extern "C" void kernel_launch(void* const* d_in, const int* in_sizes, int n_in,
                              void* d_out, int out_size, void* d_ws, size_t ws_size,
                              hipStream_t stream) {
    const float* x    = (const float*)d_in[0];
    const int*   ei   = (const int*)d_in[1];   // [2, E]
    const int*   batch= (const int*)d_in[2];
    const float* W1   = (const float*)d_in[3];
    const float* b1   = (const float*)d_in[4];
    const float* W2   = (const float*)d_in[5];
    const float* b2   = (const float*)d_in[6];
    const float* W3   = (const float*)d_in[7];
    const float* b3   = (const float*)d_in[8];
    const float* fcw1 = (const float*)d_in[9];
    const float* fcb1 = (const float*)d_in[10];
    const float* fcw2 = (const float*)d_in[11];
    const float* fcb2 = (const float*)d_in[12];
    float* out = (float*)d_out;

    const int N = in_sizes[0] / 3;      // 50000
    const int E = in_sizes[1] / 2;      // 400000
    const int Mpad = (N + 255) & ~255;  // GEMM A reads unguarded to Mpad
    const int nseg = (N + 1023) / 1024; // scan segments
    const int* row = ei;
    const int* col = ei + E;

    // ---- workspace layout ----
    size_t used = 0;
    auto need = [&](size_t bytes) {
        size_t off = used;
        used += (bytes + 255) & ~(size_t)255;
        return off;
    };
    size_t o_deg  = need((size_t)N * 4);
    size_t o_cur  = need((size_t)N * 4);
    size_t o_dis  = need((size_t)N * 4);
    size_t o_offs = need((size_t)(N + 1) * 4);
    size_t o_seg  = need((size_t)nseg * 4);
    size_t o_segb = need((size_t)nseg * 4);
    size_t o_ssrc = need((size_t)E * 4);
    size_t o_sw   = need((size_t)E * 4);
    size_t o_xp   = need((size_t)N * 16);
    size_t o_aggx = need((size_t)N * 3 * 4);
    size_t o_gsum = need((size_t)NGRAPH * 512 * 4);
    size_t o_gcnt = need((size_t)NGRAPH * 4);
    size_t o_w2t  = need((size_t)512 * 1024 * 2);
    size_t o_w3t  = need((size_t)1024 * 512 * 2);
    size_t o_bufX = need((size_t)Mpad * 512 * 2);    // h1 -> g3   (bf16)
    size_t o_bufY = need((size_t)Mpad * 512 * 2);    // agg1 -> h3 (bf16)
    size_t o_bufZ = need((size_t)Mpad * 1024 * 2);   // h2         (bf16)

    if (used > ws_size) {
        hipLaunchKernelGGL(zero_out_k, dim3((out_size + 63) / 64), dim3(64), 0, stream,
                           out, out_size);
        return;
    }

    char* base = (char*)d_ws;
    int*    deg_cnt = (int*)   (base + o_deg);
    int*    cursor  = (int*)   (base + o_cur);
    float*  dis     = (float*) (base + o_dis);
    int*    offs    = (int*)   (base + o_offs);
    int*    segsum  = (int*)   (base + o_seg);
    int*    segbase = (int*)   (base + o_segb);
    int*    ssrc    = (int*)   (base + o_ssrc);
    float*  sw      = (float*) (base + o_sw);
    float4* xp      = (float4*)(base + o_xp);
    float*  aggx    = (float*) (base + o_aggx);
    float*  gsum    = (float*) (base + o_gsum);
    int*    gcnt    = (int*)   (base + o_gcnt);
    __hip_bfloat16* w2t  = (__hip_bfloat16*)(base + o_w2t);
    __hip_bfloat16* w3t  = (__hip_bfloat16*)(base + o_w3t);
    __hip_bfloat16* bufX = (__hip_bfloat16*)(base + o_bufX);
    __hip_bfloat16* bufY = (__hip_bfloat16*)(base + o_bufY);
    __hip_bfloat16* bufZ = (__hip_bfloat16*)(base + o_bufZ);
    (void)n_in;

    int gN = (N + 255) / 256;
    int gE = (E + 255) / 256;
    int gW = (N + 3) / 4;                 // wave-per-node grids
    int nmt = Mpad / 128;                 // 392 row tiles (128 rows each)

    // CSR build (+x packing); parallel 3-phase scan
    hipLaunchKernelGGL(init_k, dim3(gN), dim3(256), 0, stream, deg_cnt, cursor, gsum, gcnt, x, xp, N);
    hipLaunchKernelGGL(deg_k, dim3(gE), dim3(256), 0, stream, col, deg_cnt, E);
    hipLaunchKernelGGL(segsum_k, dim3(nseg), dim3(256), 0, stream, deg_cnt, segsum, N);
    hipLaunchKernelGGL(segscan_k, dim3(1), dim3(64), 0, stream, segsum, segbase, offs, nseg, N);
    hipLaunchKernelGGL(offs_k, dim3(nseg), dim3(1024), 0, stream, deg_cnt, segbase, offs, dis, N);
    hipLaunchKernelGGL(scatter_k, dim3(gE), dim3(256), 0, stream, row, col, offs, cursor, ssrc, sw, dis, E);

    // weights: transpose + bf16 convert
    hipLaunchKernelGGL(tcvt_k, dim3(1024), dim3(256), 0, stream, W2, w2t, W3, w3t);

    // layer 1: agg(F=3) thread-per-node, then 3->512 GEMM wave-per-node
    hipLaunchKernelGGL(agg3_k, dim3(gN), dim3(256), 0, stream, xp, aggx, offs, ssrc, sw, dis, N);
    hipLaunchKernelGGL(gemm1_k, dim3(gW), dim3(256), 0, stream, aggx, W1, b1, bufX, N);

    // layer 2: agg1 = A_norm h1, h2 = relu(agg1 @ W2 + b2)
    hipLaunchKernelGGL(agg512w_k, dim3(gW), dim3(256), 0, stream, bufX, bufY, offs, ssrc, sw, dis,
                       (const float*)nullptr, 0, N);
    hipLaunchKernelGGL(mfma_gemm256_k, dim3(nmt * 4), dim3(512), 0, stream,
                       bufY, w2t, b2, bufZ, N, 1024, 512, 1, 2);

    // layer 3: g3 = h2 @ W3, h3 = relu(A_norm g3 + b3)
    hipLaunchKernelGGL(mfma_gemm256_k, dim3(nmt * 2), dim3(512), 0, stream,
                       bufZ, w3t, (const float*)nullptr, bufX, N, 512, 1024, 0, 1);
    hipLaunchKernelGGL(agg512w_k, dim3(gW), dim3(256), 0, stream, bufX, bufY, offs, ssrc, sw, dis,
                       b3, 1, N);

    // mean pool (+counts) + head
    hipLaunchKernelGGL(pool_k, dim3(256), dim3(256), 0, stream, bufY, batch, gsum, gcnt, N);
    hipLaunchKernelGGL(fc_k, dim3(NGRAPH), dim3(128), 0, stream, gsum, gcnt, fcw1, fcb1, fcw2, fcb2, out);
}

// Round 6
// 632.777 us; speedup vs baseline: 1.2483x; 1.2483x over previous
//
#include <hip/hip_runtime.h>
#include <hip/hip_bf16.h>

#define NNODES 50000
#define NEDGES 400000
#define NGRAPH 16

typedef __attribute__((ext_vector_type(4))) float floatx4;
typedef __attribute__((ext_vector_type(8))) short short8;

typedef __attribute__((address_space(3))) unsigned int lds_uint;
typedef __attribute__((address_space(1))) const unsigned int gbl_uint;

__device__ __forceinline__ void load16_to_lds(const void* g, void* l) {
    __builtin_amdgcn_global_load_lds((gbl_uint*)g, (lds_uint*)l, 16, 0, 0);
}

// ---------------------------------------------------------------------------
__global__ __launch_bounds__(64) void zero_out_k(float* out, int n) {
    int i = blockIdx.x * 64 + threadIdx.x;
    if (i < n) out[i] = 0.0f;
}

// init: zero counters/accumulators + pack x rows into float4
__global__ __launch_bounds__(256) void init_k(int* deg_cnt, int* cursor,
                                              float* gsum, int* gcnt,
                                              const float* __restrict__ x,
                                              float4* __restrict__ xp, int n) {
    int i = blockIdx.x * 256 + threadIdx.x;
    if (i < n) {
        deg_cnt[i] = 0; cursor[i] = 0;
        xp[i] = make_float4(x[i * 3 + 0], x[i * 3 + 1], x[i * 3 + 2], 0.0f);
    }
    if (i < NGRAPH * 512) gsum[i] = 0.0f;
    if (i < NGRAPH) gcnt[i] = 0;
}

__global__ __launch_bounds__(256) void deg_k(const int* __restrict__ col,
                                             int* __restrict__ deg_cnt, int e) {
    int i = blockIdx.x * 256 + threadIdx.x;
    if (i < e) atomicAdd(&deg_cnt[col[i]], 1);
}

// ---- parallel 3-phase scan ----
__global__ __launch_bounds__(256) void segsum_k(const int* __restrict__ cnt,
                                                int* __restrict__ segsum, int n) {
    __shared__ int sb[256];
    int seg = blockIdx.x;
    int base = seg * 1024;
    int t = threadIdx.x;
    int s = 0;
#pragma unroll
    for (int j = 0; j < 4; ++j) {
        int idx = base + t + j * 256;
        if (idx < n) s += cnt[idx];
    }
    sb[t] = s;
    __syncthreads();
    for (int off = 128; off > 0; off >>= 1) {
        if (t < off) sb[t] += sb[t + off];
        __syncthreads();
    }
    if (t == 0) segsum[seg] = sb[0];
}

__global__ __launch_bounds__(64) void segscan_k(const int* __restrict__ segsum,
                                                int* __restrict__ segbase,
                                                int* __restrict__ offs,
                                                int nseg, int n) {
    if (threadIdx.x == 0) {
        int run = 0;
        for (int s = 0; s < nseg; ++s) { segbase[s] = run; run += segsum[s]; }
        offs[n] = run;
    }
}

__global__ __launch_bounds__(1024) void offs_k(const int* __restrict__ cnt,
                                               const int* __restrict__ segbase,
                                               int* __restrict__ offs,
                                               float* __restrict__ dis, int n) {
    __shared__ int sb[1024];
    int seg = blockIdx.x;
    int t = threadIdx.x;
    int i = seg * 1024 + t;
    int c = (i < n) ? cnt[i] : 0;
    sb[t] = c;
    __syncthreads();
    for (int off = 1; off < 1024; off <<= 1) {
        int v = (t >= off) ? sb[t - off] : 0;
        __syncthreads();
        sb[t] += v;
        __syncthreads();
    }
    if (i < n) {
        offs[i] = segbase[seg] + sb[t] - c;   // exclusive prefix
        dis[i]  = rsqrtf((float)(c + 1));
    }
}

__global__ __launch_bounds__(256) void scatter_k(const int* __restrict__ row,
                                                 const int* __restrict__ col,
                                                 const int* __restrict__ offs,
                                                 int* __restrict__ cursor,
                                                 int* __restrict__ ssrc,
                                                 float* __restrict__ sw,
                                                 const float* __restrict__ dis, int e) {
    int i = blockIdx.x * 256 + threadIdx.x;
    if (i >= e) return;
    int d = col[i];
    int p = offs[d] + atomicAdd(&cursor[d], 1);
    int s = row[i];
    ssrc[p] = s;
    sw[p]   = dis[s];
}

// aggregate x (F=3)
__global__ __launch_bounds__(256) void agg3_k(const float4* __restrict__ xp,
                                              float* __restrict__ out,
                                              const int* __restrict__ offs,
                                              const int* __restrict__ ssrc,
                                              const float* __restrict__ sw,
                                              const float* __restrict__ dis, int n) {
    int d = blockIdx.x * 256 + threadIdx.x;
    if (d >= n) return;
    float dd = dis[d];
    float4 xd = xp[d];
    float a0 = dd * xd.x, a1 = dd * xd.y, a2 = dd * xd.z;
    int beg = offs[d], end = offs[d + 1];
    for (int e = beg; e < end; ++e) {
        int s = ssrc[e];
        float w = sw[e];
        float4 q = xp[s];
        a0 += w * q.x; a1 += w * q.y; a2 += w * q.z;
    }
    out[d * 3 + 0] = dd * a0;
    out[d * 3 + 1] = dd * a1;
    out[d * 3 + 2] = dd * a2;
}

// h1 = relu(aggx[N,3] @ W1[3,512] + b1) -> bf16; one WAVE per node
__global__ __launch_bounds__(256) void gemm1_k(const float* __restrict__ aggx,
                                               const float* __restrict__ W1,
                                               const float* __restrict__ b1,
                                               __hip_bfloat16* __restrict__ h1, int n) {
    int wave = threadIdx.x >> 6;
    int lane = threadIdx.x & 63;
    int d = blockIdx.x * 4 + wave;
    if (d >= n) return;
    float a0 = aggx[d * 3 + 0], a1 = aggx[d * 3 + 1], a2 = aggx[d * 3 + 2];
    int f0 = lane * 8;
    short8 ov;
#pragma unroll
    for (int j = 0; j < 8; ++j) {
        int f = f0 + j;
        float v = b1[f] + a0 * W1[f] + a1 * W1[512 + f] + a2 * W1[1024 + f];
        __hip_bfloat16 h = __float2bfloat16(fmaxf(v, 0.0f));
        ov[j] = *(short*)&h;
    }
    *(short8*)&h1[(size_t)d * 512 + f0] = ov;
}

__device__ inline float bs2f(short v) {
    return __uint_as_float(((unsigned int)(unsigned short)v) << 16);
}

// aggregation F=512: one WAVE per node; edge loop unrolled x8 (R6: deeper
// in-flight gather depth — 8 rows x 1KB = 8KB/wave in flight to cover L3
// latency), fp32 acc, bf16 out.
__global__ __launch_bounds__(256) void agg512w_k(const __hip_bfloat16* __restrict__ in,
                                                 __hip_bfloat16* __restrict__ out,
                                                 const int* __restrict__ offs,
                                                 const int* __restrict__ ssrc,
                                                 const float* __restrict__ sw,
                                                 const float* __restrict__ dis,
                                                 const float* __restrict__ bias,
                                                 int relu, int n) {
    int wave = threadIdx.x >> 6;
    int lane = threadIdx.x & 63;
    int d = blockIdx.x * 4 + wave;
    if (d >= n) return;
    float dd = dis[d];
    short8 p = *(const short8*)&in[(size_t)d * 512 + lane * 8];
    float acc[8];
#pragma unroll
    for (int j = 0; j < 8; ++j) acc[j] = dd * bs2f(p[j]);

    int beg = offs[d], end = offs[d + 1];
    int e = beg;
    for (; e + 7 < end; e += 8) {
        int   s0 = ssrc[e],     s1 = ssrc[e + 1], s2 = ssrc[e + 2], s3 = ssrc[e + 3];
        int   s4 = ssrc[e + 4], s5 = ssrc[e + 5], s6 = ssrc[e + 6], s7 = ssrc[e + 7];
        float w0 = sw[e],     w1 = sw[e + 1], w2 = sw[e + 2], w3 = sw[e + 3];
        float w4 = sw[e + 4], w5 = sw[e + 5], w6 = sw[e + 6], w7 = sw[e + 7];
        short8 q0 = *(const short8*)&in[(size_t)s0 * 512 + lane * 8];
        short8 q1 = *(const short8*)&in[(size_t)s1 * 512 + lane * 8];
        short8 q2 = *(const short8*)&in[(size_t)s2 * 512 + lane * 8];
        short8 q3 = *(const short8*)&in[(size_t)s3 * 512 + lane * 8];
        short8 q4 = *(const short8*)&in[(size_t)s4 * 512 + lane * 8];
        short8 q5 = *(const short8*)&in[(size_t)s5 * 512 + lane * 8];
        short8 q6 = *(const short8*)&in[(size_t)s6 * 512 + lane * 8];
        short8 q7 = *(const short8*)&in[(size_t)s7 * 512 + lane * 8];
#pragma unroll
        for (int j = 0; j < 8; ++j) acc[j] += w0 * bs2f(q0[j]);
#pragma unroll
        for (int j = 0; j < 8; ++j) acc[j] += w1 * bs2f(q1[j]);
#pragma unroll
        for (int j = 0; j < 8; ++j) acc[j] += w2 * bs2f(q2[j]);
#pragma unroll
        for (int j = 0; j < 8; ++j) acc[j] += w3 * bs2f(q3[j]);
#pragma unroll
        for (int j = 0; j < 8; ++j) acc[j] += w4 * bs2f(q4[j]);
#pragma unroll
        for (int j = 0; j < 8; ++j) acc[j] += w5 * bs2f(q5[j]);
#pragma unroll
        for (int j = 0; j < 8; ++j) acc[j] += w6 * bs2f(q6[j]);
#pragma unroll
        for (int j = 0; j < 8; ++j) acc[j] += w7 * bs2f(q7[j]);
    }
    for (; e + 3 < end; e += 4) {
        int s0 = ssrc[e],     s1 = ssrc[e + 1];
        int s2 = ssrc[e + 2], s3 = ssrc[e + 3];
        float w0 = sw[e],     w1 = sw[e + 1];
        float w2 = sw[e + 2], w3 = sw[e + 3];
        short8 q0 = *(const short8*)&in[(size_t)s0 * 512 + lane * 8];
        short8 q1 = *(const short8*)&in[(size_t)s1 * 512 + lane * 8];
        short8 q2 = *(const short8*)&in[(size_t)s2 * 512 + lane * 8];
        short8 q3 = *(const short8*)&in[(size_t)s3 * 512 + lane * 8];
#pragma unroll
        for (int j = 0; j < 8; ++j) acc[j] += w0 * bs2f(q0[j]);
#pragma unroll
        for (int j = 0; j < 8; ++j) acc[j] += w1 * bs2f(q1[j]);
#pragma unroll
        for (int j = 0; j < 8; ++j) acc[j] += w2 * bs2f(q2[j]);
#pragma unroll
        for (int j = 0; j < 8; ++j) acc[j] += w3 * bs2f(q3[j]);
    }
    for (; e < end; ++e) {
        int s0 = ssrc[e];
        float w0 = sw[e];
        short8 q0 = *(const short8*)&in[(size_t)s0 * 512 + lane * 8];
#pragma unroll
        for (int j = 0; j < 8; ++j) acc[j] += w0 * bs2f(q0[j]);
    }

    short8 ov;
#pragma unroll
    for (int j = 0; j < 8; ++j) {
        float v = acc[j] * dd;
        if (bias) v += bias[lane * 8 + j];
        if (relu) v = fmaxf(v, 0.0f);
        __hip_bfloat16 h = __float2bfloat16(v);
        ov[j] = *(short*)&h;
    }
    *(short8*)&out[(size_t)d * 512 + lane * 8] = ov;
}

// merged transpose+convert for BOTH weight matrices
__global__ __launch_bounds__(256) void tcvt_k(const float* __restrict__ W2,
                                              __hip_bfloat16* __restrict__ w2t,
                                              const float* __restrict__ W3,
                                              __hip_bfloat16* __restrict__ w3t) {
    __shared__ float tile[32][33];
    int t = threadIdx.x;
    const float* W; __hip_bfloat16* Wt;
    int K, N, idx;
    if (blockIdx.x < 512) { W = W2; Wt = w2t; K = 512;  N = 1024; idx = blockIdx.x; }
    else                  { W = W3; Wt = w3t; K = 1024; N = 512;  idx = blockIdx.x - 512; }
    int nbn = N / 32;
    int bn = (idx % nbn) * 32;
    int bk = (idx / nbn) * 32;
    int c = t & 31, r0 = t >> 5;
#pragma unroll
    for (int j = 0; j < 4; ++j) {
        int r = r0 + j * 8;
        tile[r][c] = W[(size_t)(bk + r) * N + bn + c];
    }
    __syncthreads();
#pragma unroll
    for (int j = 0; j < 4; ++j) {
        int r = r0 + j * 8;
        Wt[(size_t)(bn + r) * K + bk + c] = __float2bfloat16(tile[c][r]);
    }
}

// ---------------------------------------------------------------------------
// bf16 MFMA GEMM — R1 configuration (best measured: 109.7us/GEMM):
// 256x256 tile, BK=64, 8 waves, 2-slab double buffer, counted vmcnt(8),
// subtile-major conflict-free LDS, setprio, bijective XCD swizzle.
__global__ __launch_bounds__(512, 2) void mfma_gemm256_k(
        const __hip_bfloat16* __restrict__ A,
        const __hip_bfloat16* __restrict__ Bt,
        const float* __restrict__ bias,
        __hip_bfloat16* __restrict__ C,
        int M, int N, int K, int relu, int lnt) {
    __shared__ short smem[65536];   // 128 KiB: 2 slabs x (A 32K + B 32K)

    int tid  = threadIdx.x;
    int lane = tid & 63;
    int wave = tid >> 6;
    int wm = wave >> 2;            // 0..1 : row half (128 rows)
    int wn = wave & 3;             // 0..3 : col quarter (64 cols)
    int fr = lane & 15;

    // bijective XCD swizzle (grid % 8 == 0 by construction)
    int nwg = gridDim.x;
    int wg  = (blockIdx.x & 7) * (nwg >> 3) + (blockIdx.x >> 3);
    int mt  = wg >> lnt;
    int nt  = wg & ((1 << lnt) - 1);
    int bm  = mt << 8;
    int bn  = nt << 8;

    // staging: lane l = s*16 + r stages chunk (kchunk s, row r) of its subtile
    int r = lane & 15;
    int s = lane >> 4;
    const __hip_bfloat16* ga[4];
    const __hip_bfloat16* gb[4];
#pragma unroll
    for (int j = 0; j < 4; ++j) {
        int rloc = (wave * 4 + j) * 8 + (lane >> 3);   // legacy layout helper
        (void)rloc;
    }
    // subtile-major: wave w stages subtiles {w, w+8} of A and B per 32-K half
#pragma unroll
    for (int j = 0; j < 2; ++j) {
        int gsub = wave * 2 + j;               // A subtiles 0..15 per 32-K half
        ga[j] = A  + (size_t)(bm + gsub * 16 + r) * K + s * 8;
        gb[j] = Bt + (size_t)(bn + gsub * 16 + r) * K + s * 8;
        ga[j + 2] = A  + (size_t)(bm + gsub * 16 + r) * K + 32 + s * 8;
        gb[j + 2] = Bt + (size_t)(bn + gsub * 16 + r) * K + 32 + s * 8;
    }

    floatx4 acc[8][4] = {};

    auto stage = [&](int p) {
        short* sp = &smem[p * 32768];
#pragma unroll
        for (int j = 0; j < 2; ++j) {
            int gsub = wave * 2 + j;
            // kk=0 half
            load16_to_lds(ga[j],     sp + gsub * 512);
            load16_to_lds(gb[j],     sp + 16384 + gsub * 512);
            // kk=1 half
            load16_to_lds(ga[j + 2], sp + 8192 + gsub * 512);
            load16_to_lds(gb[j + 2], sp + 16384 + 8192 + gsub * 512);
            ga[j] += 64; gb[j] += 64; ga[j + 2] += 64; gb[j + 2] += 64;
        }
    };

    auto compute = [&](int p) {
        const short* sm = &smem[p * 32768];
#pragma unroll
        for (int kk = 0; kk < 2; ++kk) {
            const short* smA = sm + kk * 8192;
            const short* smB = sm + 16384 + kk * 8192;
            short8 bfr[4];
#pragma unroll
            for (int ni = 0; ni < 4; ++ni)
                bfr[ni] = *(const short8*)&smB[(wn * 4 + ni) * 512 + lane * 8];
#pragma unroll
            for (int mh = 0; mh < 2; ++mh) {
                short8 afr[4];
#pragma unroll
                for (int mi = 0; mi < 4; ++mi)
                    afr[mi] = *(const short8*)&smA[(wm * 8 + mh * 4 + mi) * 512 + lane * 8];
                __builtin_amdgcn_s_setprio(1);
#pragma unroll
                for (int mi = 0; mi < 4; ++mi)
#pragma unroll
                    for (int ni = 0; ni < 4; ++ni)
                        acc[mh * 4 + mi][ni] = __builtin_amdgcn_mfma_f32_16x16x32_bf16(
                            afr[mi], bfr[ni], acc[mh * 4 + mi][ni], 0, 0, 0);
                __builtin_amdgcn_s_setprio(0);
            }
        }
    };

    int KT = K >> 6;
    stage(0);
    for (int t = 0; t < KT; ++t) {
        int p = t & 1;
        __builtin_amdgcn_s_barrier();                       // barrier A
        if (t + 1 < KT) {
            stage(p ^ 1);
            asm volatile("s_waitcnt vmcnt(8)" ::: "memory"); // slab t landed
        } else {
            asm volatile("s_waitcnt vmcnt(0)" ::: "memory");
        }
        __builtin_amdgcn_s_barrier();                       // barrier B
        compute(p);
    }

    // ---- epilogue: stage half-tile (128x256) in LDS, vector stores ----
    short* Cs = smem;
    int l4 = lane >> 4;
#pragma unroll
    for (int h = 0; h < 2; ++h) {
        __builtin_amdgcn_s_barrier();
        if (wm == h) {
#pragma unroll
            for (int mi = 0; mi < 8; ++mi) {
#pragma unroll
                for (int ni = 0; ni < 4; ++ni) {
                    int rr = mi * 16 + l4 * 4;
                    int cc = wn * 64 + ni * 16 + fr;
                    float bv = bias ? bias[bn + cc] : 0.0f;
#pragma unroll
                    for (int q = 0; q < 4; ++q) {
                        float v = acc[mi][ni][q] + bv;
                        if (relu) v = fmaxf(v, 0.0f);
                        __hip_bfloat16 hh = __float2bfloat16(v);
                        Cs[(rr + q) * 264 + cc] = *(short*)&hh;
                    }
                }
            }
        }
        asm volatile("s_waitcnt lgkmcnt(0)" ::: "memory");
        __builtin_amdgcn_s_barrier();
#pragma unroll
        for (int i = 0; i < 8; ++i) {
            int idx = tid + 512 * i;
            int rr = idx >> 5, cc = idx & 31;
            int grow = bm + h * 128 + rr;
            if (grow < M)
                *(short8*)&C[(size_t)grow * N + bn + cc * 8] =
                    *(const short8*)&Cs[rr * 264 + cc * 8];
        }
    }
}

// pooled sums (bf16 input, LDS fp32 accumulators) + fused per-graph counts
__global__ __launch_bounds__(256) void pool_k(const __hip_bfloat16* __restrict__ h,
                                              const int* __restrict__ batch,
                                              float* __restrict__ gsum,
                                              int* __restrict__ gcnt, int n) {
    __shared__ float ls[NGRAPH * 512];
    __shared__ int lcnt[NGRAPH];
    int t = threadIdx.x;
    for (int i = t; i < NGRAPH * 512; i += 256) ls[i] = 0.0f;
    if (t < NGRAPH) lcnt[t] = 0;
    __syncthreads();
    for (int d = blockIdx.x; d < n; d += gridDim.x) {
        int g = batch[d];
        if (t == 0) atomicAdd(&lcnt[g], 1);
        unsigned int q = *(const unsigned int*)&h[(size_t)d * 512 + 2 * t];
        ls[g * 512 + 2 * t]     += __uint_as_float((q & 0xffffu) << 16);
        ls[g * 512 + 2 * t + 1] += __uint_as_float((q >> 16) << 16);
    }
    __syncthreads();
    for (int i = t; i < NGRAPH * 512; i += 256) atomicAdd(&gsum[i], ls[i]);
    if (t < NGRAPH) atomicAdd(&gcnt[t], lcnt[t]);
}

// head MLP (fp32)
__global__ __launch_bounds__(128) void fc_k(const float* __restrict__ gsum,
                                            const int* __restrict__ gcnt,
                                            const float* __restrict__ fcw1,
                                            const float* __restrict__ fcb1,
                                            const float* __restrict__ fcw2,
                                            const float* __restrict__ fcb2,
                                            float* __restrict__ out) {
    int g = blockIdx.x;
    int t = threadIdx.x;  // 128
    __shared__ float pooled[512];
    __shared__ float red[128];
    float inv = 1.0f / fmaxf((float)gcnt[g], 1.0f);
    for (int i = t; i < 512; i += 128) pooled[i] = gsum[g * 512 + i] * inv;
    __syncthreads();
    float sacc = fcb1[t];
    for (int k = 0; k < 512; ++k) sacc += pooled[k] * fcw1[k * 128 + t];
    sacc = fmaxf(sacc, 0.0f);
    red[t] = sacc * fcw2[t];
    __syncthreads();
    for (int off = 64; off > 0; off >>= 1) {
        if (t < off) red[t] += red[t + off];
        __syncthreads();
    }
    if (t == 0) out[g] = red[0] + fcb2[0];
}

extern "C" void kernel_launch(void* const* d_in, const int* in_sizes, int n_in,
                              void* d_out, int out_size, void* d_ws, size_t ws_size,
                              hipStream_t stream) {
    const float* x    = (const float*)d_in[0];
    const int*   ei   = (const int*)d_in[1];   // [2, E]
    const int*   batch= (const int*)d_in[2];
    const float* W1   = (const float*)d_in[3];
    const float* b1   = (const float*)d_in[4];
    const float* W2   = (const float*)d_in[5];
    const float* b2   = (const float*)d_in[6];
    const float* W3   = (const float*)d_in[7];
    const float* b3   = (const float*)d_in[8];
    const float* fcw1 = (const float*)d_in[9];
    const float* fcb1 = (const float*)d_in[10];
    const float* fcw2 = (const float*)d_in[11];
    const float* fcb2 = (const float*)d_in[12];
    float* out = (float*)d_out;

    const int N = in_sizes[0] / 3;      // 50000
    const int E = in_sizes[1] / 2;      // 400000
    const int Mpad = (N + 255) & ~255;  // 256-row GEMM tiles read unguarded to Mpad
    const int nseg = (N + 1023) / 1024; // scan segments
    const int* row = ei;
    const int* col = ei + E;

    // ---- workspace layout ----
    size_t used = 0;
    auto need = [&](size_t bytes) {
        size_t off = used;
        used += (bytes + 255) & ~(size_t)255;
        return off;
    };
    size_t o_deg  = need((size_t)N * 4);
    size_t o_cur  = need((size_t)N * 4);
    size_t o_dis  = need((size_t)N * 4);
    size_t o_offs = need((size_t)(N + 1) * 4);
    size_t o_seg  = need((size_t)nseg * 4);
    size_t o_segb = need((size_t)nseg * 4);
    size_t o_ssrc = need((size_t)E * 4);
    size_t o_sw   = need((size_t)E * 4);
    size_t o_xp   = need((size_t)N * 16);
    size_t o_aggx = need((size_t)N * 3 * 4);
    size_t o_gsum = need((size_t)NGRAPH * 512 * 4);
    size_t o_gcnt = need((size_t)NGRAPH * 4);
    size_t o_w2t  = need((size_t)512 * 1024 * 2);
    size_t o_w3t  = need((size_t)1024 * 512 * 2);
    size_t o_bufX = need((size_t)Mpad * 512 * 2);    // h1 -> g3   (bf16)
    size_t o_bufY = need((size_t)Mpad * 512 * 2);    // agg1 -> h3 (bf16)
    size_t o_bufZ = need((size_t)Mpad * 1024 * 2);   // h2         (bf16)

    if (used > ws_size) {
        hipLaunchKernelGGL(zero_out_k, dim3((out_size + 63) / 64), dim3(64), 0, stream,
                           out, out_size);
        return;
    }

    char* base = (char*)d_ws;
    int*    deg_cnt = (int*)   (base + o_deg);
    int*    cursor  = (int*)   (base + o_cur);
    float*  dis     = (float*) (base + o_dis);
    int*    offs    = (int*)   (base + o_offs);
    int*    segsum  = (int*)   (base + o_seg);
    int*    segbase = (int*)   (base + o_segb);
    int*    ssrc    = (int*)   (base + o_ssrc);
    float*  sw      = (float*) (base + o_sw);
    float4* xp      = (float4*)(base + o_xp);
    float*  aggx    = (float*) (base + o_aggx);
    float*  gsum    = (float*) (base + o_gsum);
    int*    gcnt    = (int*)   (base + o_gcnt);
    __hip_bfloat16* w2t  = (__hip_bfloat16*)(base + o_w2t);
    __hip_bfloat16* w3t  = (__hip_bfloat16*)(base + o_w3t);
    __hip_bfloat16* bufX = (__hip_bfloat16*)(base + o_bufX);
    __hip_bfloat16* bufY = (__hip_bfloat16*)(base + o_bufY);
    __hip_bfloat16* bufZ = (__hip_bfloat16*)(base + o_bufZ);
    (void)n_in;

    int gN = (N + 255) / 256;
    int gE = (E + 255) / 256;
    int gW = (N + 3) / 4;                 // wave-per-node grids
    int nrt = Mpad / 256;                 // 196 row tiles (256 rows each)

    // CSR build (+x packing); parallel 3-phase scan
    hipLaunchKernelGGL(init_k, dim3(gN), dim3(256), 0, stream, deg_cnt, cursor, gsum, gcnt, x, xp, N);
    hipLaunchKernelGGL(deg_k, dim3(gE), dim3(256), 0, stream, col, deg_cnt, E);
    hipLaunchKernelGGL(segsum_k, dim3(nseg), dim3(256), 0, stream, deg_cnt, segsum, N);
    hipLaunchKernelGGL(segscan_k, dim3(1), dim3(64), 0, stream, segsum, segbase, offs, nseg, N);
    hipLaunchKernelGGL(offs_k, dim3(nseg), dim3(1024), 0, stream, deg_cnt, segbase, offs, dis, N);
    hipLaunchKernelGGL(scatter_k, dim3(gE), dim3(256), 0, stream, row, col, offs, cursor, ssrc, sw, dis, E);

    // weights: transpose + bf16 convert
    hipLaunchKernelGGL(tcvt_k, dim3(1024), dim3(256), 0, stream, W2, w2t, W3, w3t);

    // layer 1: agg(F=3) thread-per-node, then 3->512 GEMM wave-per-node
    hipLaunchKernelGGL(agg3_k, dim3(gN), dim3(256), 0, stream, xp, aggx, offs, ssrc, sw, dis, N);
    hipLaunchKernelGGL(gemm1_k, dim3(gW), dim3(256), 0, stream, aggx, W1, b1, bufX, N);

    // layer 2: agg1 = A_norm h1, h2 = relu(agg1 @ W2 + b2)
    hipLaunchKernelGGL(agg512w_k, dim3(gW), dim3(256), 0, stream, bufX, bufY, offs, ssrc, sw, dis,
                       (const float*)nullptr, 0, N);
    hipLaunchKernelGGL(mfma_gemm256_k, dim3(nrt * 4), dim3(512), 0, stream,
                       bufY, w2t, b2, bufZ, N, 1024, 512, 1, 2);

    // layer 3: g3 = h2 @ W3, h3 = relu(A_norm g3 + b3)
    hipLaunchKernelGGL(mfma_gemm256_k, dim3(nrt * 2), dim3(512), 0, stream,
                       bufZ, w3t, (const float*)nullptr, bufX, N, 512, 1024, 0, 1);
    hipLaunchKernelGGL(agg512w_k, dim3(gW), dim3(256), 0, stream, bufX, bufY, offs, ssrc, sw, dis,
                       b3, 1, N);

    // mean pool (+counts) + head
    hipLaunchKernelGGL(pool_k, dim3(256), dim3(256), 0, stream, bufY, batch, gsum, gcnt, N);
    hipLaunchKernelGGL(fc_k, dim3(NGRAPH), dim3(128), 0, stream, gsum, gcnt, fcw1, fcb1, fcw2, fcb2, out);
}

// Round 7
// 502.106 us; speedup vs baseline: 1.5731x; 1.2602x over previous
//
#include <hip/hip_runtime.h>
#include <hip/hip_bf16.h>

#define NNODES 50000
#define NEDGES 400000
#define NGRAPH 16
#define NBG 64   // blocks per graph in fused agg+pool

typedef __attribute__((ext_vector_type(4))) float floatx4;
typedef __attribute__((ext_vector_type(8))) short short8;

typedef __attribute__((address_space(3))) unsigned int lds_uint;
typedef __attribute__((address_space(1))) const unsigned int gbl_uint;

__device__ __forceinline__ void load16_to_lds(const void* g, void* l) {
    __builtin_amdgcn_global_load_lds((gbl_uint*)g, (lds_uint*)l, 16, 0, 0);
}

// ---------------------------------------------------------------------------
__global__ __launch_bounds__(64) void zero_out_k(float* out, int n) {
    int i = blockIdx.x * 64 + threadIdx.x;
    if (i < n) out[i] = 0.0f;
}

// init: zero counters/accumulators + pack x rows into float4 + graph histogram
__global__ __launch_bounds__(256) void init_k(int* deg_cnt, int* cursor,
                                              float* gsum, int* gdeg,
                                              const float* __restrict__ x,
                                              float4* __restrict__ xp,
                                              const int* __restrict__ batch, int n) {
    __shared__ int h[NGRAPH];
    int t = threadIdx.x;
    if (t < NGRAPH) h[t] = 0;
    __syncthreads();
    int i = blockIdx.x * 256 + t;
    if (i < n) {
        deg_cnt[i] = 0; cursor[i] = 0;
        xp[i] = make_float4(x[i * 3 + 0], x[i * 3 + 1], x[i * 3 + 2], 0.0f);
        atomicAdd(&h[batch[i]], 1);
    }
    if (i < NGRAPH * 512) gsum[i] = 0.0f;
    __syncthreads();
    if (t < NGRAPH && h[t]) atomicAdd(&gdeg[t], h[t]);
}

__global__ __launch_bounds__(256) void deg_k(const int* __restrict__ col,
                                             int* __restrict__ deg_cnt, int e) {
    int i = blockIdx.x * 256 + threadIdx.x;
    if (i < e) atomicAdd(&deg_cnt[col[i]], 1);
}

// ---- parallel 3-phase scan ----
__global__ __launch_bounds__(256) void segsum_k(const int* __restrict__ cnt,
                                                int* __restrict__ segsum, int n) {
    __shared__ int sb[256];
    int seg = blockIdx.x;
    int base = seg * 1024;
    int t = threadIdx.x;
    int s = 0;
#pragma unroll
    for (int j = 0; j < 4; ++j) {
        int idx = base + t + j * 256;
        if (idx < n) s += cnt[idx];
    }
    sb[t] = s;
    __syncthreads();
    for (int off = 128; off > 0; off >>= 1) {
        if (t < off) sb[t] += sb[t + off];
        __syncthreads();
    }
    if (t == 0) segsum[seg] = sb[0];
}

__global__ __launch_bounds__(64) void segscan_k(const int* __restrict__ segsum,
                                                int* __restrict__ segbase,
                                                int* __restrict__ offs,
                                                int nseg, int n) {
    if (threadIdx.x == 0) {
        int run = 0;
        for (int s = 0; s < nseg; ++s) { segbase[s] = run; run += segsum[s]; }
        offs[n] = run;
    }
}

__global__ __launch_bounds__(1024) void offs_k(const int* __restrict__ cnt,
                                               const int* __restrict__ segbase,
                                               int* __restrict__ offs,
                                               float* __restrict__ dis, int n) {
    __shared__ int sb[1024];
    int seg = blockIdx.x;
    int t = threadIdx.x;
    int i = seg * 1024 + t;
    int c = (i < n) ? cnt[i] : 0;
    sb[t] = c;
    __syncthreads();
    for (int off = 1; off < 1024; off <<= 1) {
        int v = (t >= off) ? sb[t - off] : 0;
        __syncthreads();
        sb[t] += v;
        __syncthreads();
    }
    if (i < n) {
        offs[i] = segbase[seg] + sb[t] - c;   // exclusive prefix
        dis[i]  = rsqrtf((float)(c + 1));
    }
}

__global__ __launch_bounds__(256) void scatter_k(const int* __restrict__ row,
                                                 const int* __restrict__ col,
                                                 const int* __restrict__ offs,
                                                 int* __restrict__ cursor,
                                                 int* __restrict__ ssrc,
                                                 float* __restrict__ sw,
                                                 const float* __restrict__ dis, int e) {
    int i = blockIdx.x * 256 + threadIdx.x;
    if (i >= e) return;
    int d = col[i];
    int p = offs[d] + atomicAdd(&cursor[d], 1);
    int s = row[i];
    ssrc[p] = s;
    sw[p]   = dis[s];
}

// graph-bucket prefix (16 entries, serial)
__global__ __launch_bounds__(64) void gpfx_k(const int* __restrict__ gdeg,
                                             int* __restrict__ goffs) {
    if (threadIdx.x == 0) {
        int run = 0;
        for (int g = 0; g < NGRAPH; ++g) { goffs[g] = run; run += gdeg[g]; }
    }
}

// place node ids grouped by graph (block-batched to avoid 16-counter contention)
__global__ __launch_bounds__(256) void gplace_k(const int* __restrict__ batch,
                                                const int* __restrict__ goffs,
                                                int* __restrict__ gcur,
                                                int* __restrict__ perm, int n) {
    __shared__ int h[NGRAPH];
    __shared__ int basev[NGRAPH];
    int t = threadIdx.x;
    if (t < NGRAPH) h[t] = 0;
    __syncthreads();
    int i = blockIdx.x * 256 + t;
    int g = 0, r = 0;
    if (i < n) {
        g = batch[i];
        r = atomicAdd(&h[g], 1);
    }
    __syncthreads();
    if (t < NGRAPH) basev[t] = h[t] ? atomicAdd(&gcur[t], h[t]) : 0;
    __syncthreads();
    if (i < n) perm[goffs[g] + basev[g] + r] = i;
}

// aggregate x (F=3)
__global__ __launch_bounds__(256) void agg3_k(const float4* __restrict__ xp,
                                              float* __restrict__ out,
                                              const int* __restrict__ offs,
                                              const int* __restrict__ ssrc,
                                              const float* __restrict__ sw,
                                              const float* __restrict__ dis, int n) {
    int d = blockIdx.x * 256 + threadIdx.x;
    if (d >= n) return;
    float dd = dis[d];
    float4 xd = xp[d];
    float a0 = dd * xd.x, a1 = dd * xd.y, a2 = dd * xd.z;
    int beg = offs[d], end = offs[d + 1];
    for (int e = beg; e < end; ++e) {
        int s = ssrc[e];
        float w = sw[e];
        float4 q = xp[s];
        a0 += w * q.x; a1 += w * q.y; a2 += w * q.z;
    }
    out[d * 3 + 0] = dd * a0;
    out[d * 3 + 1] = dd * a1;
    out[d * 3 + 2] = dd * a2;
}

// h1 = relu(aggx[N,3] @ W1[3,512] + b1) -> bf16; one WAVE per node
__global__ __launch_bounds__(256) void gemm1_k(const float* __restrict__ aggx,
                                               const float* __restrict__ W1,
                                               const float* __restrict__ b1,
                                               __hip_bfloat16* __restrict__ h1, int n) {
    int wave = threadIdx.x >> 6;
    int lane = threadIdx.x & 63;
    int d = blockIdx.x * 4 + wave;
    if (d >= n) return;
    float a0 = aggx[d * 3 + 0], a1 = aggx[d * 3 + 1], a2 = aggx[d * 3 + 2];
    int f0 = lane * 8;
    short8 ov;
#pragma unroll
    for (int j = 0; j < 8; ++j) {
        int f = f0 + j;
        float v = b1[f] + a0 * W1[f] + a1 * W1[512 + f] + a2 * W1[1024 + f];
        __hip_bfloat16 h = __float2bfloat16(fmaxf(v, 0.0f));
        ov[j] = *(short*)&h;
    }
    *(short8*)&h1[(size_t)d * 512 + f0] = ov;
}

__device__ inline float bs2f(short v) {
    return __uint_as_float(((unsigned int)(unsigned short)v) << 16);
}

// aggregation F=512: one WAVE per node (layer 2: no bias, no relu)
__global__ __launch_bounds__(256) void agg512w_k(const __hip_bfloat16* __restrict__ in,
                                                 __hip_bfloat16* __restrict__ out,
                                                 const int* __restrict__ offs,
                                                 const int* __restrict__ ssrc,
                                                 const float* __restrict__ sw,
                                                 const float* __restrict__ dis, int n) {
    int wave = threadIdx.x >> 6;
    int lane = threadIdx.x & 63;
    int d = blockIdx.x * 4 + wave;
    if (d >= n) return;
    float dd = dis[d];
    short8 p = *(const short8*)&in[(size_t)d * 512 + lane * 8];
    float acc[8];
#pragma unroll
    for (int j = 0; j < 8; ++j) acc[j] = dd * bs2f(p[j]);

    int beg = offs[d], end = offs[d + 1];
    int e = beg;
    for (; e + 3 < end; e += 4) {
        int s0 = ssrc[e],     s1 = ssrc[e + 1];
        int s2 = ssrc[e + 2], s3 = ssrc[e + 3];
        float w0 = sw[e],     w1 = sw[e + 1];
        float w2 = sw[e + 2], w3 = sw[e + 3];
        short8 q0 = *(const short8*)&in[(size_t)s0 * 512 + lane * 8];
        short8 q1 = *(const short8*)&in[(size_t)s1 * 512 + lane * 8];
        short8 q2 = *(const short8*)&in[(size_t)s2 * 512 + lane * 8];
        short8 q3 = *(const short8*)&in[(size_t)s3 * 512 + lane * 8];
#pragma unroll
        for (int j = 0; j < 8; ++j) acc[j] += w0 * bs2f(q0[j]);
#pragma unroll
        for (int j = 0; j < 8; ++j) acc[j] += w1 * bs2f(q1[j]);
#pragma unroll
        for (int j = 0; j < 8; ++j) acc[j] += w2 * bs2f(q2[j]);
#pragma unroll
        for (int j = 0; j < 8; ++j) acc[j] += w3 * bs2f(q3[j]);
    }
    for (; e < end; ++e) {
        int s0 = ssrc[e];
        float w0 = sw[e];
        short8 q0 = *(const short8*)&in[(size_t)s0 * 512 + lane * 8];
#pragma unroll
        for (int j = 0; j < 8; ++j) acc[j] += w0 * bs2f(q0[j]);
    }

    short8 ov;
#pragma unroll
    for (int j = 0; j < 8; ++j) {
        __hip_bfloat16 h = __float2bfloat16(acc[j] * dd);
        ov[j] = *(short*)&h;
    }
    *(short8*)&out[(size_t)d * 512 + lane * 8] = ov;
}

// FUSED layer-3 aggregation + mean-pool partial sums (R7):
// h3 rows are never written to global. Each block handles nodes of ONE graph
// (via perm/goffs), accumulates relu(agg*dd + b3) into a per-wave LDS buffer
// (conflict-free float4 RMW), and flushes one atomicAdd per feature per block.
__global__ __launch_bounds__(256) void aggpool_k(const __hip_bfloat16* __restrict__ in,
                                                 const int* __restrict__ perm,
                                                 const int* __restrict__ goffs,
                                                 const int* __restrict__ gdeg,
                                                 const int* __restrict__ offs,
                                                 const int* __restrict__ ssrc,
                                                 const float* __restrict__ sw,
                                                 const float* __restrict__ dis,
                                                 const float* __restrict__ bias,
                                                 float* __restrict__ gsum) {
    __shared__ float lsw[4 * 512];
    int t = threadIdx.x;
    int wave = t >> 6;
    int lane = t & 63;
    int g = blockIdx.x & (NGRAPH - 1);
    int s = blockIdx.x >> 4;
    for (int i = t; i < 4 * 512; i += 256) lsw[i] = 0.0f;
    int cnt = gdeg[g];
    int per = (cnt + NBG - 1) / NBG;
    int beg = s * per;
    int end = min(cnt, beg + per);
    int gb  = goffs[g];
    float bj[8];
#pragma unroll
    for (int j = 0; j < 8; ++j) bj[j] = bias[lane * 8 + j];
    __syncthreads();

    for (int ii = beg + wave; ii < end; ii += 4) {
        int d = perm[gb + ii];
        float dd = dis[d];
        short8 p = *(const short8*)&in[(size_t)d * 512 + lane * 8];
        float acc[8];
#pragma unroll
        for (int j = 0; j < 8; ++j) acc[j] = dd * bs2f(p[j]);

        int eb = offs[d], ee = offs[d + 1];
        int e = eb;
        for (; e + 3 < ee; e += 4) {
            int s0 = ssrc[e],     s1 = ssrc[e + 1];
            int s2 = ssrc[e + 2], s3 = ssrc[e + 3];
            float w0 = sw[e],     w1 = sw[e + 1];
            float w2 = sw[e + 2], w3 = sw[e + 3];
            short8 q0 = *(const short8*)&in[(size_t)s0 * 512 + lane * 8];
            short8 q1 = *(const short8*)&in[(size_t)s1 * 512 + lane * 8];
            short8 q2 = *(const short8*)&in[(size_t)s2 * 512 + lane * 8];
            short8 q3 = *(const short8*)&in[(size_t)s3 * 512 + lane * 8];
#pragma unroll
            for (int j = 0; j < 8; ++j) acc[j] += w0 * bs2f(q0[j]);
#pragma unroll
            for (int j = 0; j < 8; ++j) acc[j] += w1 * bs2f(q1[j]);
#pragma unroll
            for (int j = 0; j < 8; ++j) acc[j] += w2 * bs2f(q2[j]);
#pragma unroll
            for (int j = 0; j < 8; ++j) acc[j] += w3 * bs2f(q3[j]);
        }
        for (; e < ee; ++e) {
            int s0 = ssrc[e];
            float w0 = sw[e];
            short8 q0 = *(const short8*)&in[(size_t)s0 * 512 + lane * 8];
#pragma unroll
            for (int j = 0; j < 8; ++j) acc[j] += w0 * bs2f(q0[j]);
        }

        float* mb = &lsw[wave * 512 + lane * 8];
        float4 a0 = *(float4*)mb;
        float4 a1 = *((float4*)mb + 1);
        a0.x += fmaxf(acc[0] * dd + bj[0], 0.0f);
        a0.y += fmaxf(acc[1] * dd + bj[1], 0.0f);
        a0.z += fmaxf(acc[2] * dd + bj[2], 0.0f);
        a0.w += fmaxf(acc[3] * dd + bj[3], 0.0f);
        a1.x += fmaxf(acc[4] * dd + bj[4], 0.0f);
        a1.y += fmaxf(acc[5] * dd + bj[5], 0.0f);
        a1.z += fmaxf(acc[6] * dd + bj[6], 0.0f);
        a1.w += fmaxf(acc[7] * dd + bj[7], 0.0f);
        *(float4*)mb = a0;
        *((float4*)mb + 1) = a1;
    }
    __syncthreads();
    for (int f = t; f < 512; f += 256) {
        float v = lsw[f] + lsw[512 + f] + lsw[1024 + f] + lsw[1536 + f];
        atomicAdd(&gsum[g * 512 + f], v);
    }
}

// merged transpose+convert for BOTH weight matrices
__global__ __launch_bounds__(256) void tcvt_k(const float* __restrict__ W2,
                                              __hip_bfloat16* __restrict__ w2t,
                                              const float* __restrict__ W3,
                                              __hip_bfloat16* __restrict__ w3t) {
    __shared__ float tile[32][33];
    int t = threadIdx.x;
    const float* W; __hip_bfloat16* Wt;
    int K, N, idx;
    if (blockIdx.x < 512) { W = W2; Wt = w2t; K = 512;  N = 1024; idx = blockIdx.x; }
    else                  { W = W3; Wt = w3t; K = 1024; N = 512;  idx = blockIdx.x - 512; }
    int nbn = N / 32;
    int bn = (idx % nbn) * 32;
    int bk = (idx / nbn) * 32;
    int c = t & 31, r0 = t >> 5;
#pragma unroll
    for (int j = 0; j < 4; ++j) {
        int r = r0 + j * 8;
        tile[r][c] = W[(size_t)(bk + r) * N + bn + c];
    }
    __syncthreads();
#pragma unroll
    for (int j = 0; j < 4; ++j) {
        int r = r0 + j * 8;
        Wt[(size_t)(bn + r) * K + bk + c] = __float2bfloat16(tile[c][r]);
    }
}

// ---------------------------------------------------------------------------
// bf16 MFMA GEMM — byte-exact R1 structure (best measured: 109.7us/GEMM):
// 256x256 tile, BK=64, 8 waves, 2-slab double buffer, counted vmcnt(8),
// XOR slot-swizzle (keeps 128B-contiguous global segments), setprio,
// bijective XCD swizzle.
__global__ __launch_bounds__(512, 2) void mfma_gemm256_k(
        const __hip_bfloat16* __restrict__ A,
        const __hip_bfloat16* __restrict__ Bt,
        const float* __restrict__ bias,
        __hip_bfloat16* __restrict__ C,
        int M, int N, int K, int relu, int lnt) {
    __shared__ short smem[65536];   // 128 KiB: 2 slabs x (A 32K + B 32K)

    int tid  = threadIdx.x;
    int lane = tid & 63;
    int wave = tid >> 6;
    int wm = wave >> 2;            // 0..1 : row half (128 rows)
    int wn = wave & 3;             // 0..3 : col quarter (64 cols)
    int fr = lane & 15;
    int kg = lane >> 4;
    int f7 = fr & 7;

    // bijective XCD swizzle (grid % 8 == 0 by construction)
    int nwg = gridDim.x;
    int wg  = (blockIdx.x & 7) * (nwg >> 3) + (blockIdx.x >> 3);
    int mt  = wg >> lnt;
    int nt  = wg & ((1 << lnt) - 1);
    int bm  = mt << 8;
    int bn  = nt << 8;

    // staging source pointers (pre-swizzled global addresses):
    // lane l writes LDS phys slot (l&7) of row 8m+(l>>3); data there must be
    // logical slot (l&7)^((l>>3)&7) — per-row 128B global segments stay whole.
    int rsub = lane >> 3;                 // 0..7
    int slog = (lane & 7) ^ rsub;         // logical 16B slot (k block)
    const __hip_bfloat16* ga[4];
    const __hip_bfloat16* gb[4];
#pragma unroll
    for (int j = 0; j < 4; ++j) {
        int rloc = (wave * 4 + j) * 8 + rsub;          // tile row 0..255
        ga[j] = A  + (size_t)(bm + rloc) * K + slog * 8;
        gb[j] = Bt + (size_t)(bn + rloc) * K + slog * 8;
    }
    int dstA = wave * 2048;               // short index of this wave's A chunk

    // fragment read offsets (short index, swizzled)
    int aoff = (wm * 128 + fr) * 64 + ((kg ^ f7) * 8);
    int boff = 16384 + (wn * 64 + fr) * 64 + ((kg ^ f7) * 8);

    floatx4 acc[8][4] = {};

    auto stage = [&](int p) {
        short* sp = &smem[p * 32768];
#pragma unroll
        for (int j = 0; j < 4; ++j) {
            load16_to_lds(ga[j], sp + dstA + j * 512);
            load16_to_lds(gb[j], sp + 16384 + dstA + j * 512);
            ga[j] += 64;
            gb[j] += 64;
        }
    };

    stage(0);
    int KT = K >> 6;
    for (int t = 0; t < KT; ++t) {
        int p = t & 1;
        __builtin_amdgcn_s_barrier();                       // barrier A
        if (t + 1 < KT) {
            stage(p ^ 1);
            asm volatile("s_waitcnt vmcnt(8)" ::: "memory"); // slab t landed
        } else {
            asm volatile("s_waitcnt vmcnt(0)" ::: "memory");
        }
        __builtin_amdgcn_s_barrier();                       // barrier B

        const short* sm = &smem[p * 32768];
#pragma unroll
        for (int ks = 0; ks < 2; ++ks) {
            int kx = ks * 32;
            short8 bfr[4];
#pragma unroll
            for (int ni = 0; ni < 4; ++ni)
                bfr[ni] = *(const short8*)&sm[(boff + ni * 1024) ^ kx];
#pragma unroll
            for (int mh = 0; mh < 2; ++mh) {
                short8 afr[4];
#pragma unroll
                for (int mi = 0; mi < 4; ++mi)
                    afr[mi] = *(const short8*)&sm[(aoff + (mh * 4 + mi) * 1024) ^ kx];
                __builtin_amdgcn_s_setprio(1);
#pragma unroll
                for (int mi = 0; mi < 4; ++mi)
#pragma unroll
                    for (int ni = 0; ni < 4; ++ni)
                        acc[mh * 4 + mi][ni] = __builtin_amdgcn_mfma_f32_16x16x32_bf16(
                            afr[mi], bfr[ni], acc[mh * 4 + mi][ni], 0, 0, 0);
                __builtin_amdgcn_s_setprio(0);
            }
        }
    }

    // ---- epilogue: stage half-tile (128x256) in LDS, vector stores ----
    short* Cs = smem;
    int l4 = lane >> 4;
#pragma unroll
    for (int h = 0; h < 2; ++h) {
        __builtin_amdgcn_s_barrier();    // all ds_reads of last slab issued
        if (wm == h) {
#pragma unroll
            for (int mi = 0; mi < 8; ++mi) {
#pragma unroll
                for (int ni = 0; ni < 4; ++ni) {
                    int rr = mi * 16 + l4 * 4;
                    int cc = wn * 64 + ni * 16 + fr;
                    float bv = bias ? bias[bn + cc] : 0.0f;
#pragma unroll
                    for (int r = 0; r < 4; ++r) {
                        float v = acc[mi][ni][r] + bv;
                        if (relu) v = fmaxf(v, 0.0f);
                        __hip_bfloat16 hh = __float2bfloat16(v);
                        Cs[(rr + r) * 264 + cc] = *(short*)&hh;
                    }
                }
            }
        }
        asm volatile("s_waitcnt lgkmcnt(0)" ::: "memory");
        __builtin_amdgcn_s_barrier();
#pragma unroll
        for (int i = 0; i < 8; ++i) {
            int idx = tid + 512 * i;
            int rr = idx >> 5, cc = idx & 31;
            int grow = bm + h * 128 + rr;
            if (grow < M)
                *(short8*)&C[(size_t)grow * N + bn + cc * 8] =
                    *(const short8*)&Cs[rr * 264 + cc * 8];
        }
    }
}

// head MLP (fp32)
__global__ __launch_bounds__(128) void fc_k(const float* __restrict__ gsum,
                                            const int* __restrict__ gdeg,
                                            const float* __restrict__ fcw1,
                                            const float* __restrict__ fcb1,
                                            const float* __restrict__ fcw2,
                                            const float* __restrict__ fcb2,
                                            float* __restrict__ out) {
    int g = blockIdx.x;
    int t = threadIdx.x;  // 128
    __shared__ float pooled[512];
    __shared__ float red[128];
    float inv = 1.0f / fmaxf((float)gdeg[g], 1.0f);
    for (int i = t; i < 512; i += 128) pooled[i] = gsum[g * 512 + i] * inv;
    __syncthreads();
    float sacc = fcb1[t];
    for (int k = 0; k < 512; ++k) sacc += pooled[k] * fcw1[k * 128 + t];
    sacc = fmaxf(sacc, 0.0f);
    red[t] = sacc * fcw2[t];
    __syncthreads();
    for (int off = 64; off > 0; off >>= 1) {
        if (t < off) red[t] += red[t + off];
        __syncthreads();
    }
    if (t == 0) out[g] = red[0] + fcb2[0];
}

extern "C" void kernel_launch(void* const* d_in, const int* in_sizes, int n_in,
                              void* d_out, int out_size, void* d_ws, size_t ws_size,
                              hipStream_t stream) {
    const float* x    = (const float*)d_in[0];
    const int*   ei   = (const int*)d_in[1];   // [2, E]
    const int*   batch= (const int*)d_in[2];
    const float* W1   = (const float*)d_in[3];
    const float* b1   = (const float*)d_in[4];
    const float* W2   = (const float*)d_in[5];
    const float* b2   = (const float*)d_in[6];
    const float* W3   = (const float*)d_in[7];
    const float* b3   = (const float*)d_in[8];
    const float* fcw1 = (const float*)d_in[9];
    const float* fcb1 = (const float*)d_in[10];
    const float* fcw2 = (const float*)d_in[11];
    const float* fcb2 = (const float*)d_in[12];
    float* out = (float*)d_out;

    const int N = in_sizes[0] / 3;      // 50000
    const int E = in_sizes[1] / 2;      // 400000
    const int Mpad = (N + 255) & ~255;  // 256-row GEMM tiles read unguarded to Mpad
    const int nseg = (N + 1023) / 1024; // scan segments
    const int* row = ei;
    const int* col = ei + E;

    // ---- workspace layout ----
    size_t used = 0;
    auto need = [&](size_t bytes) {
        size_t off = used;
        used += (bytes + 255) & ~(size_t)255;
        return off;
    };
    size_t o_deg  = need((size_t)N * 4);
    size_t o_cur  = need((size_t)N * 4);
    size_t o_dis  = need((size_t)N * 4);
    size_t o_offs = need((size_t)(N + 1) * 4);
    size_t o_seg  = need((size_t)nseg * 4);
    size_t o_segb = need((size_t)nseg * 4);
    size_t o_ssrc = need((size_t)E * 4);
    size_t o_sw   = need((size_t)E * 4);
    size_t o_xp   = need((size_t)N * 16);
    size_t o_aggx = need((size_t)N * 3 * 4);
    size_t o_gsum = need((size_t)NGRAPH * 512 * 4);
    size_t o_gdeg = need((size_t)NGRAPH * 4);    // graph node counts
    size_t o_gcur = need((size_t)NGRAPH * 4);    // graph cursors
    size_t o_goff = need((size_t)(NGRAPH + 1) * 4);
    size_t o_perm = need((size_t)N * 4);         // nodes grouped by graph
    size_t o_w2t  = need((size_t)512 * 1024 * 2);
    size_t o_w3t  = need((size_t)1024 * 512 * 2);
    size_t o_bufX = need((size_t)Mpad * 512 * 2);    // h1 -> g3   (bf16)
    size_t o_bufY = need((size_t)Mpad * 512 * 2);    // agg1       (bf16)
    size_t o_bufZ = need((size_t)Mpad * 1024 * 2);   // h2         (bf16)

    if (used > ws_size) {
        hipLaunchKernelGGL(zero_out_k, dim3((out_size + 63) / 64), dim3(64), 0, stream,
                           out, out_size);
        return;
    }

    char* base = (char*)d_ws;
    int*    deg_cnt = (int*)   (base + o_deg);
    int*    cursor  = (int*)   (base + o_cur);
    float*  dis     = (float*) (base + o_dis);
    int*    offs    = (int*)   (base + o_offs);
    int*    segsum  = (int*)   (base + o_seg);
    int*    segbase = (int*)   (base + o_segb);
    int*    ssrc    = (int*)   (base + o_ssrc);
    float*  sw      = (float*) (base + o_sw);
    float4* xp      = (float4*)(base + o_xp);
    float*  aggx    = (float*) (base + o_aggx);
    float*  gsum    = (float*) (base + o_gsum);
    int*    gdeg    = (int*)   (base + o_gdeg);
    int*    gcur    = (int*)   (base + o_gcur);
    int*    goffs   = (int*)   (base + o_goff);
    int*    perm    = (int*)   (base + o_perm);
    __hip_bfloat16* w2t  = (__hip_bfloat16*)(base + o_w2t);
    __hip_bfloat16* w3t  = (__hip_bfloat16*)(base + o_w3t);
    __hip_bfloat16* bufX = (__hip_bfloat16*)(base + o_bufX);
    __hip_bfloat16* bufY = (__hip_bfloat16*)(base + o_bufY);
    __hip_bfloat16* bufZ = (__hip_bfloat16*)(base + o_bufZ);
    (void)n_in;

    int gN = (N + 255) / 256;
    int gE = (E + 255) / 256;
    int gW = (N + 3) / 4;                 // wave-per-node grids
    int nrt = Mpad / 256;                 // 196 row tiles (256 rows each)

    // zero the small graph counters (gdeg + gcur, two aligned 256B blocks)
    hipMemsetAsync(base + o_gdeg, 0, 512, stream);

    // CSR build (+x packing +graph histogram); parallel 3-phase scan
    hipLaunchKernelGGL(init_k, dim3(gN), dim3(256), 0, stream, deg_cnt, cursor, gsum, gdeg, x, xp, batch, N);
    hipLaunchKernelGGL(deg_k, dim3(gE), dim3(256), 0, stream, col, deg_cnt, E);
    hipLaunchKernelGGL(segsum_k, dim3(nseg), dim3(256), 0, stream, deg_cnt, segsum, N);
    hipLaunchKernelGGL(segscan_k, dim3(1), dim3(64), 0, stream, segsum, segbase, offs, nseg, N);
    hipLaunchKernelGGL(offs_k, dim3(nseg), dim3(1024), 0, stream, deg_cnt, segbase, offs, dis, N);
    hipLaunchKernelGGL(scatter_k, dim3(gE), dim3(256), 0, stream, row, col, offs, cursor, ssrc, sw, dis, E);

    // graph grouping for the fused agg+pool
    hipLaunchKernelGGL(gpfx_k, dim3(1), dim3(64), 0, stream, gdeg, goffs);
    hipLaunchKernelGGL(gplace_k, dim3(gN), dim3(256), 0, stream, batch, goffs, gcur, perm, N);

    // weights: transpose + bf16 convert
    hipLaunchKernelGGL(tcvt_k, dim3(1024), dim3(256), 0, stream, W2, w2t, W3, w3t);

    // layer 1: agg(F=3) thread-per-node, then 3->512 GEMM wave-per-node
    hipLaunchKernelGGL(agg3_k, dim3(gN), dim3(256), 0, stream, xp, aggx, offs, ssrc, sw, dis, N);
    hipLaunchKernelGGL(gemm1_k, dim3(gW), dim3(256), 0, stream, aggx, W1, b1, bufX, N);

    // layer 2: agg1 = A_norm h1, h2 = relu(agg1 @ W2 + b2)
    hipLaunchKernelGGL(agg512w_k, dim3(gW), dim3(256), 0, stream, bufX, bufY, offs, ssrc, sw, dis, N);
    hipLaunchKernelGGL(mfma_gemm256_k, dim3(nrt * 4), dim3(512), 0, stream,
                       bufY, w2t, b2, bufZ, N, 1024, 512, 1, 2);

    // layer 3: g3 = h2 @ W3; fused h3 = relu(A_norm g3 + b3) + mean-pool sums
    hipLaunchKernelGGL(mfma_gemm256_k, dim3(nrt * 2), dim3(512), 0, stream,
                       bufZ, w3t, (const float*)nullptr, bufX, N, 512, 1024, 0, 1);
    hipLaunchKernelGGL(aggpool_k, dim3(NGRAPH * NBG), dim3(256), 0, stream,
                       bufX, perm, goffs, gdeg, offs, ssrc, sw, dis, b3, gsum);

    // head
    hipLaunchKernelGGL(fc_k, dim3(NGRAPH), dim3(128), 0, stream, gsum, gdeg, fcw1, fcb1, fcw2, fcb2, out);
}